// Round 5
// baseline (290.015 us; speedup 1.0000x reference)
//
#include <hip/hip_runtime.h>
#include <hip/hip_bf16.h>

// Fused Interaction Estimator, v5: ZERO-BARRIER wave-independent design.
// Each 64-thread block = 1 wave = 32 complete rows (all 256 cols).
// LN/dots/fusion are within-wave shuffle reductions -> no __syncthreads
// anywhere, so no vmcnt(0) drains; loads stay in flight continuously.
// A-fragments load directly from global (f32 -> bf16 in regs); W fragments
// stream from L2 (packed by prep kernel); alignG parks in wave-private LDS
// as bf16 to keep VGPR under the 256 cap (launch_bounds(64,2)).

typedef float f32x4 __attribute__((ext_vector_type(4)));
typedef short short8 __attribute__((ext_vector_type(8)));
typedef unsigned int u32;

#define D_DIM 256

union S8 { short8 s; u32 u[4]; };

__device__ __forceinline__ u32 f2bfu(float x) {   // RNE f32->bf16 (finite)
  u32 u = __float_as_uint(x);
  return (u + 0x7FFFu + ((u >> 16) & 1u)) >> 16;
}
__device__ __forceinline__ u32 pk2(float a, float b) {
  return f2bfu(a) | (f2bfu(b) << 16);
}
__device__ __forceinline__ float bflo(u32 u) { return __uint_as_float(u << 16); }
__device__ __forceinline__ float bfhi(u32 u) { return __uint_as_float(u & 0xffff0000u); }
__device__ __forceinline__ float sigm(float x) { return 1.0f / (1.0f + __expf(-x)); }

// load 8 consecutive f32 and pack to a bf16 MFMA fragment
__device__ __forceinline__ short8 ldA(const float* __restrict__ p) {
  float4 lo = *(const float4*)p;
  float4 hi = *(const float4*)(p + 4);
  S8 r;
  r.u[0] = pk2(lo.x, lo.y);
  r.u[1] = pk2(lo.z, lo.w);
  r.u[2] = pk2(hi.x, hi.y);
  r.u[3] = pk2(hi.z, hi.w);
  return r.s;
}

// ---------------- prep: pack W (f32 [k][m] row-major) into bf16 MFMA B-fragment order ----
// chunk = (c*8 + t)*64 + l holds 8 bf16: B[k = t*32 + (l>>4)*8 + j][m = c*16 + (l&15)]
__global__ __launch_bounds__(256) void pack_w_kernel(const float* __restrict__ Wg,
                                                     const float* __restrict__ Wp,
                                                     unsigned short* __restrict__ outp) {
  int b = blockIdx.x;
  const float* W = (b < 32) ? Wg : Wp;
  unsigned short* o = outp + (b < 32 ? 0 : 65536);
  int chunk = (b & 31) * 256 + threadIdx.x;
  int c = chunk >> 9;
  int rest = chunk & 511;
  int t = rest >> 6;
  int l = rest & 63;
  int m = c * 16 + (l & 15);
  int kb = t * 32 + ((l >> 4) << 3);
  short8 v;
#pragma unroll
  for (int j = 0; j < 8; ++j) v[j] = (short)f2bfu(W[(kb + j) * 256 + m]);
  *(short8*)(o + (size_t)chunk * 8) = v;
}

// ---------------- one branch: gemm(32x256 @ 256x256) + bias + LN + ReLU + dot(align, wa) ----
__device__ __forceinline__ void do_branch(
    const float* __restrict__ A, const short8* __restrict__ wb,
    const float* __restrict__ bias, const float* __restrict__ gam,
    const float* __restrict__ bet, const float* __restrict__ wa,
    int lane, f32x4 acc[2][16], float dotv[8])
{
  const int cl = lane & 15, kg = lane >> 4;
  const float* ab = A + cl * D_DIM + kg * 8;

#pragma unroll
  for (int rt = 0; rt < 2; ++rt)
#pragma unroll
    for (int ct = 0; ct < 16; ++ct) acc[rt][ct] = {0.f, 0.f, 0.f, 0.f};

#pragma unroll
  for (int t = 0; t < 8; ++t) {
    short8 a0 = ldA(ab + t * 32);
    short8 a1 = ldA(ab + 16 * D_DIM + t * 32);
#pragma unroll
    for (int ct = 0; ct < 16; ++ct) {
      short8 b = wb[(ct * 8 + t) * 64 + lane];
      acc[0][ct] = __builtin_amdgcn_mfma_f32_16x16x32_bf16(a0, b, acc[0][ct], 0, 0, 0);
      acc[1][ct] = __builtin_amdgcn_mfma_f32_16x16x32_bf16(a1, b, acc[1][ct], 0, 0, 0);
    }
  }

  // bias + row stats (sum, sumsq) — rows are (rt*16 + kg*4 + rr), cols in cl-group
  float s[8], q[8];
#pragma unroll
  for (int i = 0; i < 8; ++i) { s[i] = 0.f; q[i] = 0.f; }
#pragma unroll
  for (int ct = 0; ct < 16; ++ct) {
    float bb = bias[ct * 16 + cl];
#pragma unroll
    for (int rt = 0; rt < 2; ++rt)
#pragma unroll
      for (int rr = 0; rr < 4; ++rr) {
        float y = acc[rt][ct][rr] + bb;
        acc[rt][ct][rr] = y;
        s[rt * 4 + rr] += y;
        q[rt * 4 + rr] += y * y;
      }
  }
  float mu[8], rs[8];
#pragma unroll
  for (int i = 0; i < 8; ++i) {
    float ss = s[i], qq = q[i];
#pragma unroll
    for (int m = 1; m < 16; m <<= 1) { ss += __shfl_xor(ss, m, 64); qq += __shfl_xor(qq, m, 64); }
    float mm = ss * (1.0f / 256.0f);
    float vv = fmaxf(qq * (1.0f / 256.0f) - mm * mm, 0.0f);
    mu[i] = mm;
    rs[i] = rsqrtf(vv + 1e-5f);
  }

  // LN + ReLU (in place) + dot(align, wa)
  float dp[8];
#pragma unroll
  for (int i = 0; i < 8; ++i) dp[i] = 0.f;
#pragma unroll
  for (int ct = 0; ct < 16; ++ct) {
    float gg = gam[ct * 16 + cl], bb = bet[ct * 16 + cl], ww = wa[ct * 16 + cl];
#pragma unroll
    for (int rt = 0; rt < 2; ++rt)
#pragma unroll
      for (int rr = 0; rr < 4; ++rr) {
        int i = rt * 4 + rr;
        float al = (acc[rt][ct][rr] - mu[i]) * rs[i] * gg + bb;
        al = fmaxf(al, 0.0f);
        acc[rt][ct][rr] = al;
        dp[i] += al * ww;
      }
  }
#pragma unroll
  for (int i = 0; i < 8; ++i) {
    float d = dp[i];
#pragma unroll
    for (int m = 1; m < 16; m <<= 1) d += __shfl_xor(d, m, 64);
    dotv[i] = d;
  }
}

__global__ __launch_bounds__(64, 2) void fused_main(
    const float* __restrict__ gfeat, const float* __restrict__ pfeat,
    const float* __restrict__ bg, const float* __restrict__ glng, const float* __restrict__ glnb,
    const float* __restrict__ bp, const float* __restrict__ plng, const float* __restrict__ plnb,
    const float* __restrict__ wag, const float* __restrict__ bag,
    const float* __restrict__ wap, const float* __restrict__ bap,
    const unsigned short* __restrict__ wpk,
    float* __restrict__ outp)
{
  __shared__ u32 agbuf[4096];   // 16 KB: wave-private bf16 park of alignG

  const int lane = threadIdx.x;         // 64-thread block = 1 wave
  const int cl = lane & 15, kg = lane >> 4;
  const size_t row0 = (size_t)blockIdx.x * 32;

  f32x4 acc[2][16];
  float gdot[8], pdot[8];

  // ---- g branch: alignG in acc, gdot = g_align . wa_p
  do_branch(gfeat + row0 * D_DIM, (const short8*)wpk,
            bg, glng, glnb, wap, lane, acc, gdot);

  // park alignG as bf16 in LDS (frees acc for the p branch)
#pragma unroll
  for (int rt = 0; rt < 2; ++rt)
#pragma unroll
    for (int ct = 0; ct < 16; ++ct) {
      int idx = ((rt * 16 + ct) * 64 + lane) * 2;
      agbuf[idx]     = pk2(acc[rt][ct][0], acc[rt][ct][1]);
      agbuf[idx + 1] = pk2(acc[rt][ct][2], acc[rt][ct][3]);
    }

  // ---- p branch: alignP in acc, pdot = p_align . wa_g
  do_branch(pfeat + row0 * D_DIM, (const short8*)(wpk + 65536),
            bp, plng, plnb, wag, lane, acc, pdot);

  // ---- fusion + store
  const float vbag = bag[0], vbap = bap[0];
  float* ob = outp + row0 * D_DIM + cl;
#pragma unroll
  for (int rt = 0; rt < 2; ++rt)
#pragma unroll
    for (int ct = 0; ct < 16; ++ct) {
      int idx = ((rt * 16 + ct) * 64 + lane) * 2;
      u32 glo = agbuf[idx], ghi = agbuf[idx + 1];
      float ga[4] = { bflo(glo), bfhi(glo), bflo(ghi), bfhi(ghi) };
#pragma unroll
      for (int rr = 0; rr < 4; ++rr) {
        int i = rt * 4 + rr;
        float pa = acc[rt][ct][rr];
        float geno = sigm(ga[rr] * pdot[i] + vbag);   // sigmoid(g_align * (p.wa_g) + ba_g)
        float path = sigm(pa * gdot[i] + vbap);       // sigmoid(p_align * (g.wa_p) + ba_p)
        ob[(size_t)(rt * 16 + kg * 4 + rr) * D_DIM + ct * 16] = pa * path + ga[rr] * geno;
      }
    }
}

extern "C" void kernel_launch(void* const* d_in, const int* in_sizes, int n_in,
                              void* d_out, int out_size, void* d_ws, size_t ws_size,
                              hipStream_t stream) {
  const float* gfeat = (const float*)d_in[0];
  const float* pfeat = (const float*)d_in[1];
  const float* Wg   = (const float*)d_in[2];
  const float* bg   = (const float*)d_in[3];
  const float* glng = (const float*)d_in[4];
  const float* glnb = (const float*)d_in[5];
  const float* Wp   = (const float*)d_in[6];
  const float* bp   = (const float*)d_in[7];
  const float* plng = (const float*)d_in[8];
  const float* plnb = (const float*)d_in[9];
  const float* wag  = (const float*)d_in[10];
  const float* bag  = (const float*)d_in[11];
  const float* wap  = (const float*)d_in[12];
  const float* bap  = (const float*)d_in[13];
  float* outp = (float*)d_out;
  unsigned short* wpk = (unsigned short*)d_ws;   // 256 KB used

  hipLaunchKernelGGL(pack_w_kernel, dim3(64), dim3(256), 0, stream, Wg, Wp, wpk);

  int nrows = in_sizes[0] / D_DIM;   // 98304
  int njobs = nrows / 32;            // 3072 one-wave jobs
  hipLaunchKernelGGL(fused_main, dim3(njobs), dim3(64), 0, stream,
                     gfeat, pfeat, bg, glng, glnb, bp, plng, plnb,
                     wag, bag, wap, bap, wpk, outp);
}